// Round 2
// baseline (3462.157 us; speedup 1.0000x reference)
//
#include <hip/hip_runtime.h>
#include <hip/hip_bf16.h>

#define D 128
#define NROW 50000      // N_U == N_V == 50000
#define NEDGE 640000

// ============================================================
// GEMM + bias: Y[r][j] = sum_k X[r][k] * W[k][j] + b[j]   (all fp32)
// X: [nrows x 128], W: [128 x 128], b: [128], Y: [nrows x 128]
// Block: 256 threads, 32-row tile. Thread: 4 rows x 4 cols (cols cc+32j).
// W staged k-packed in LDS: Wp[kb*128+j] = float4(W[4kb..4kb+3][j]) so
// consecutive lanes (cc) read consecutive float4 -> conflict-free ds_read_b128.
// ============================================================
__global__ __launch_bounds__(256) void gemm_bias(const float* __restrict__ X,
                                                 const float* __restrict__ W,
                                                 const float* __restrict__ b,
                                                 float* __restrict__ Y, int nrows) {
    __shared__ float4 Wp[32 * 128];   // 64 KB
    __shared__ float4 Xs[32 * 32];    // 16 KB  (rows of 128 f32 as 32 float4)

    const int tid = threadIdx.x;

    // ---- stage W (k-packed); j contiguous across lanes -> coalesced ----
    {
        int j = tid & 127;
        int h = tid >> 7;  // 0..1
        for (int kb = h; kb < 32; kb += 2) {
            float4 w;
            w.x = W[(4 * kb + 0) * D + j];
            w.y = W[(4 * kb + 1) * D + j];
            w.z = W[(4 * kb + 2) * D + j];
            w.w = W[(4 * kb + 3) * D + j];
            Wp[kb * 128 + j] = w;
        }
    }

    // ---- stage X tile (32 rows), float4 coalesced ----
    const int row0 = blockIdx.x * 32;
    {
        int k4 = tid & 31;       // float4 index within row
        int rb = tid >> 5;       // 0..7
        for (int i = 0; i < 4; i++) {
            int r = rb + 8 * i;
            int gr = row0 + r;
            float4 v = make_float4(0.f, 0.f, 0.f, 0.f);
            if (gr < nrows) v = ((const float4*)(X + (size_t)gr * D))[k4];
            Xs[r * 32 + k4] = v;
        }
    }
    __syncthreads();

    const int cc = tid & 31;   // cols: cc, cc+32, cc+64, cc+96
    const int rr = tid >> 5;   // rows: rr*4 .. rr*4+3

    float acc[4][4];
#pragma unroll
    for (int i = 0; i < 4; i++)
#pragma unroll
        for (int j = 0; j < 4; j++) acc[i][j] = 0.f;

#pragma unroll 4
    for (int kb = 0; kb < 32; kb++) {
        float4 w[4];
#pragma unroll
        for (int j = 0; j < 4; j++) w[j] = Wp[kb * 128 + cc + 32 * j];
        float4 a[4];
#pragma unroll
        for (int i = 0; i < 4; i++) a[i] = Xs[(rr * 4 + i) * 32 + kb];
#pragma unroll
        for (int i = 0; i < 4; i++) {
#pragma unroll
            for (int j = 0; j < 4; j++) {
                acc[i][j] += a[i].x * w[j].x;
                acc[i][j] += a[i].y * w[j].y;
                acc[i][j] += a[i].z * w[j].z;
                acc[i][j] += a[i].w * w[j].w;
            }
        }
    }

    // ---- epilogue: bias + store ----
#pragma unroll
    for (int i = 0; i < 4; i++) {
        int gr = row0 + rr * 4 + i;
        if (gr < nrows) {
            float* yr = Y + (size_t)gr * D;
#pragma unroll
            for (int j = 0; j < 4; j++) yr[cc + 32 * j] = acc[i][j] + b[cc + 32 * j];
        }
    }
}

// ============================================================
// scatter_add: B[dst[e]][:] += A[src[e]][:]  (segment_sum over edges)
// 32 lanes per edge, float4 gather, 4x fp32 global atomic add (no-return).
// ============================================================
__global__ __launch_bounds__(256) void scatter_add(const float* __restrict__ A,
                                                   const int* __restrict__ src_idx,
                                                   const int* __restrict__ dst_idx,
                                                   float* __restrict__ B) {
    int e = blockIdx.x * 8 + (threadIdx.x >> 5);
    if (e >= NEDGE) return;
    int lane = threadIdx.x & 31;
    int s = src_idx[e];
    int d = dst_idx[e];
    float4 v = ((const float4*)(A + (size_t)s * D))[lane];
    float* out = B + (size_t)d * D + lane * 4;
    unsafeAtomicAdd(out + 0, v.x);
    unsafeAtomicAdd(out + 1, v.y);
    unsafeAtomicAdd(out + 2, v.z);
    unsafeAtomicAdd(out + 3, v.w);
}

// ============================================================
__global__ __launch_bounds__(256) void zero_f32(float4* __restrict__ p, int n4) {
    int i = blockIdx.x * 256 + threadIdx.x;
    if (i < n4) p[i] = make_float4(0.f, 0.f, 0.f, 0.f);
}

// ============================================================
extern "C" void kernel_launch(void* const* d_in, const int* in_sizes, int n_in,
                              void* d_out, int out_size, void* d_ws, size_t ws_size,
                              hipStream_t stream) {
    // inputs: 0=X_u(unused), 1=X_v, 2=edge_u, 3=edge_v, 4=W0, 5=b0, 6=W1, 7=b1, 8=W2, 9=b2
    const float* X_v = (const float*)d_in[1];
    const int* edge_u = (const int*)d_in[2];
    const int* edge_v = (const int*)d_in[3];
    const float* W0 = (const float*)d_in[4];
    const float* b0 = (const float*)d_in[5];
    const float* W1 = (const float*)d_in[6];
    const float* b1 = (const float*)d_in[7];
    const float* W2 = (const float*)d_in[8];
    const float* b2 = (const float*)d_in[9];

    float* A = (float*)d_ws;          // 50000*128 f32 = 25.6 MB (only ws use)
    float* OUT = (float*)d_out;       // final output doubles as scatter dst

    const int n4 = NROW * D / 4;                 // 1.6M float4
    const dim3 blk(256);
    const int gemm_grid = (NROW + 31) / 32;      // 1563
    const int zero_grid = (n4 + 255) / 256;      // 6250
    const int scat_grid = (NEDGE + 7) / 8;       // 80000

    // layer 0: A = X_v @ W0 + b0 ; OUT = v2u(A)  (gather edge_v, scatter edge_u)
    gemm_bias<<<gemm_grid, blk, 0, stream>>>(X_v, W0, b0, A, NROW);
    zero_f32<<<zero_grid, blk, 0, stream>>>((float4*)OUT, n4);
    scatter_add<<<scat_grid, blk, 0, stream>>>(A, edge_v, edge_u, OUT);

    // layer 1: A = OUT @ W1 + b1 ; OUT = u2v(A)  (gather edge_u, scatter edge_v)
    gemm_bias<<<gemm_grid, blk, 0, stream>>>(OUT, W1, b1, A, NROW);
    zero_f32<<<zero_grid, blk, 0, stream>>>((float4*)OUT, n4);
    scatter_add<<<scat_grid, blk, 0, stream>>>(A, edge_u, edge_v, OUT);

    // layer 2: A = OUT @ W2 + b2 ; OUT = v2u(A)
    gemm_bias<<<gemm_grid, blk, 0, stream>>>(OUT, W2, b2, A, NROW);
    zero_f32<<<zero_grid, blk, 0, stream>>>((float4*)OUT, n4);
    scatter_add<<<scat_grid, blk, 0, stream>>>(A, edge_v, edge_u, OUT);
}

// Round 3
// 569.992 us; speedup vs baseline: 6.0740x; 6.0740x over previous
//
#include <hip/hip_runtime.h>

#define D 128
#define NROW 50000      // N_U == N_V == 50000
#define NEDGE 640000

__device__ __forceinline__ float bf2f(unsigned short u) {
    return __uint_as_float(((unsigned)u) << 16);
}
__device__ __forceinline__ unsigned short f2bf(float f) {
    unsigned u = __float_as_uint(f);
    unsigned r = (u + 0x7fff + ((u >> 16) & 1)) >> 16;  // round-nearest-even
    return (unsigned short)r;
}

// ============================================================
// GEMM + bias: Y[r][j] = bf16( sum_k X[r][k] * W[k][j] + b[j] )
// X fp32 [nrows x 128], W fp32 [128 x 128], b fp32 [128], Y bf16.
// Block: 256 threads, 32-row tile. Thread: 4 rows x 4 cols (cols cc+32j).
// Wp k-packed float4 so consecutive lanes read consecutive float4 (no conflicts).
// ============================================================
__global__ __launch_bounds__(256) void gemm_bias(const float* __restrict__ X,
                                                 const float* __restrict__ W,
                                                 const float* __restrict__ b,
                                                 unsigned short* __restrict__ Y, int nrows) {
    __shared__ float4 Wp[32 * 128];   // 64 KB
    __shared__ float4 Xs[32 * 32];    // 16 KB

    const int tid = threadIdx.x;

    {   // stage W (k-packed), coalesced over j
        int j = tid & 127;
        int h = tid >> 7;  // 0..1
        for (int kb = h; kb < 32; kb += 2) {
            float4 w;
            w.x = W[(4 * kb + 0) * D + j];
            w.y = W[(4 * kb + 1) * D + j];
            w.z = W[(4 * kb + 2) * D + j];
            w.w = W[(4 * kb + 3) * D + j];
            Wp[kb * 128 + j] = w;
        }
    }

    const int row0 = blockIdx.x * 32;
    {   // stage X tile (32 rows), float4 coalesced
        int k4 = tid & 31;
        int rb = tid >> 5;
        for (int i = 0; i < 4; i++) {
            int r = rb + 8 * i;
            int gr = row0 + r;
            float4 v = make_float4(0.f, 0.f, 0.f, 0.f);
            if (gr < nrows) v = ((const float4*)(X + (size_t)gr * D))[k4];
            Xs[r * 32 + k4] = v;
        }
    }
    __syncthreads();

    const int cc = tid & 31;
    const int rr = tid >> 5;

    float acc[4][4];
#pragma unroll
    for (int i = 0; i < 4; i++)
#pragma unroll
        for (int j = 0; j < 4; j++) acc[i][j] = 0.f;

#pragma unroll 4
    for (int kb = 0; kb < 32; kb++) {
        float4 w[4];
#pragma unroll
        for (int j = 0; j < 4; j++) w[j] = Wp[kb * 128 + cc + 32 * j];
        float4 a[4];
#pragma unroll
        for (int i = 0; i < 4; i++) a[i] = Xs[(rr * 4 + i) * 32 + kb];
#pragma unroll
        for (int i = 0; i < 4; i++) {
#pragma unroll
            for (int j = 0; j < 4; j++) {
                acc[i][j] += a[i].x * w[j].x;
                acc[i][j] += a[i].y * w[j].y;
                acc[i][j] += a[i].z * w[j].z;
                acc[i][j] += a[i].w * w[j].w;
            }
        }
    }

#pragma unroll
    for (int i = 0; i < 4; i++) {
        int gr = row0 + rr * 4 + i;
        if (gr < nrows) {
            unsigned short* yr = Y + (size_t)gr * D;
#pragma unroll
            for (int j = 0; j < 4; j++) yr[cc + 32 * j] = f2bf(acc[i][j] + b[cc + 32 * j]);
        }
    }
}

// ============================================================
// CSR build (per launch; edges fixed within a launch)
// ============================================================
__global__ __launch_bounds__(256) void zero_int(int* __restrict__ p, int n) {
    int i = blockIdx.x * 256 + threadIdx.x;
    if (i < n) p[i] = 0;
}

__global__ __launch_bounds__(256) void hist_deg(const int* __restrict__ eu,
                                                const int* __restrict__ ev,
                                                int* __restrict__ cu, int* __restrict__ cv) {
    int e = blockIdx.x * 256 + threadIdx.x;
    if (e >= NEDGE) return;
    atomicAdd(&cu[eu[e]], 1);
    atomicAdd(&cv[ev[e]], 1);
}

// exclusive scan of cur -> off, also cur := off (fill cursor). grid=2 (u,v).
__global__ __launch_bounds__(1024) void scan_two(int* __restrict__ cur_u, int* __restrict__ off_u,
                                                 int* __restrict__ cur_v, int* __restrict__ off_v,
                                                 int n) {
    int* cur = (blockIdx.x == 0) ? cur_u : cur_v;
    int* off = (blockIdx.x == 0) ? off_u : off_v;
    __shared__ int buf[1024];
    __shared__ int sbase;
    if (threadIdx.x == 0) sbase = 0;
    __syncthreads();
    int nchunk = (n + 1023) / 1024;
    for (int c = 0; c < nchunk; c++) {
        int g = c * 1024 + threadIdx.x;
        int x = (g < n) ? cur[g] : 0;
        buf[threadIdx.x] = x;
        __syncthreads();
        for (int o = 1; o < 1024; o <<= 1) {
            int y = (threadIdx.x >= o) ? buf[threadIdx.x - o] : 0;
            __syncthreads();
            buf[threadIdx.x] += y;
            __syncthreads();
        }
        int excl = sbase + buf[threadIdx.x] - x;
        if (g < n) { off[g] = excl; cur[g] = excl; }
        __syncthreads();
        if (threadIdx.x == 1023) sbase += buf[1023];
        __syncthreads();
    }
    if (threadIdx.x == 0) off[n] = sbase;
}

__global__ __launch_bounds__(256) void fill_csr(const int* __restrict__ eu,
                                                const int* __restrict__ ev,
                                                int* __restrict__ cu, int* __restrict__ cv,
                                                int* __restrict__ srt_u, int* __restrict__ srt_v) {
    int e = blockIdx.x * 256 + threadIdx.x;
    if (e >= NEDGE) return;
    int u = eu[e], v = ev[e];
    int p = atomicAdd(&cu[u], 1); srt_u[p] = v;   // u's segment lists v-sources
    int q = atomicAdd(&cv[v], 1); srt_v[q] = u;   // v's segment lists u-sources
}

// ============================================================
// gather_rows: OUT[r][:] = sum_{i in [off[r],off[r+1])} A[srt[i]][:]
// One wave (64 lanes) per dst row; lane l handles cols 2l, 2l+1 (bf16x2 load).
// Writes every row exactly once (no zeroing, no atomics).
// ============================================================
__global__ __launch_bounds__(256) void gather_rows(const unsigned short* __restrict__ A,
                                                   const int* __restrict__ off,
                                                   const int* __restrict__ srt,
                                                   float* __restrict__ OUT) {
    int r = blockIdx.x * 4 + (threadIdx.x >> 6);
    if (r >= NROW) return;
    int lane = threadIdx.x & 63;
    int beg = off[r], end = off[r + 1];
    float ax = 0.f, ay = 0.f;
    int i = beg;
    for (; i + 2 <= end; i += 2) {
        int s0 = srt[i], s1 = srt[i + 1];
        unsigned u0 = *(const unsigned*)(A + (size_t)s0 * D + lane * 2);
        unsigned u1 = *(const unsigned*)(A + (size_t)s1 * D + lane * 2);
        ax += bf2f((unsigned short)(u0 & 0xffff)) + bf2f((unsigned short)(u1 & 0xffff));
        ay += bf2f((unsigned short)(u0 >> 16)) + bf2f((unsigned short)(u1 >> 16));
    }
    if (i < end) {
        int s = srt[i];
        unsigned u0 = *(const unsigned*)(A + (size_t)s * D + lane * 2);
        ax += bf2f((unsigned short)(u0 & 0xffff));
        ay += bf2f((unsigned short)(u0 >> 16));
    }
    ((float2*)(OUT + (size_t)r * D))[lane] = make_float2(ax, ay);
}

// ============================================================
extern "C" void kernel_launch(void* const* d_in, const int* in_sizes, int n_in,
                              void* d_out, int out_size, void* d_ws, size_t ws_size,
                              hipStream_t stream) {
    // 0=X_u(unused), 1=X_v, 2=edge_u, 3=edge_v, 4=W0, 5=b0, 6=W1, 7=b1, 8=W2, 9=b2
    const float* X_v = (const float*)d_in[1];
    const int* edge_u = (const int*)d_in[2];
    const int* edge_v = (const int*)d_in[3];
    const float* W0 = (const float*)d_in[4];
    const float* b0 = (const float*)d_in[5];
    const float* W1 = (const float*)d_in[6];
    const float* b1 = (const float*)d_in[7];
    const float* W2 = (const float*)d_in[8];
    const float* b2 = (const float*)d_in[9];

    // ws layout (total ~18.7 MB; round 2 proved ws >= 25.6 MB)
    char* w = (char*)d_ws;
    unsigned short* A = (unsigned short*)w;            // 50000*128 bf16 = 12.8 MB
    int* srt_u = (int*)(w + 12800000);                 // 640000
    int* srt_v = srt_u + NEDGE;                        // 640000
    int* off_u = srt_v + NEDGE;                        // 50001 (pad to 50004)
    int* off_v = off_u + 50004;                        // 50001
    int* cur_u = off_v + 50004;                        // 50000
    int* cur_v = cur_u + NROW;                         // 50000 (contiguous after cur_u)

    float* OUT = (float*)d_out;

    const dim3 blk(256);
    const int gemm_grid = (NROW + 31) / 32;            // 1563
    const int edge_grid = (NEDGE + 255) / 256;         // 2500
    const int gath_grid = (NROW + 3) / 4;              // 12500

    // ---- build CSR for both directions (once per launch) ----
    zero_int<<<(2 * NROW + 255) / 256, blk, 0, stream>>>(cur_u, 2 * NROW);
    hist_deg<<<edge_grid, blk, 0, stream>>>(edge_u, edge_v, cur_u, cur_v);
    scan_two<<<2, dim3(1024), 0, stream>>>(cur_u, off_u, cur_v, off_v, NROW);
    fill_csr<<<edge_grid, blk, 0, stream>>>(edge_u, edge_v, cur_u, cur_v, srt_u, srt_v);

    // layer 0: A = bf16(X_v @ W0 + b0) ; OUT = v2u(A)  (per-u sum of A[v])
    gemm_bias<<<gemm_grid, blk, 0, stream>>>(X_v, W0, b0, A, NROW);
    gather_rows<<<gath_grid, blk, 0, stream>>>(A, off_u, srt_u, OUT);

    // layer 1: A = bf16(OUT @ W1 + b1) ; OUT = u2v(A)  (per-v sum of A[u])
    gemm_bias<<<gemm_grid, blk, 0, stream>>>(OUT, W1, b1, A, NROW);
    gather_rows<<<gath_grid, blk, 0, stream>>>(A, off_v, srt_v, OUT);

    // layer 2: A = bf16(OUT @ W2 + b2) ; OUT = v2u(A)
    gemm_bias<<<gemm_grid, blk, 0, stream>>>(OUT, W2, b2, A, NROW);
    gather_rows<<<gath_grid, blk, 0, stream>>>(A, off_u, srt_u, OUT);
}

// Round 4
// 455.852 us; speedup vs baseline: 7.5949x; 1.2504x over previous
//
#include <hip/hip_runtime.h>

#define D 128
#define NROW 50000      // N_U == N_V == 50000
#define NEDGE 640000

__device__ __forceinline__ float bf2f(unsigned short u) {
    return __uint_as_float(((unsigned)u) << 16);
}
__device__ __forceinline__ unsigned short f2bf(float f) {
    unsigned u = __float_as_uint(f);
    unsigned r = (u + 0x7fff + ((u >> 16) & 1)) >> 16;  // round-nearest-even
    return (unsigned short)r;
}

// ============================================================
// fp32 -> bf16 row conversion (Xv -> Xb)
// ============================================================
__global__ __launch_bounds__(256) void cvt_bf16(const float4* __restrict__ in,
                                                ushort4* __restrict__ out, int n4) {
    int i = blockIdx.x * 256 + threadIdx.x;
    if (i < n4) {
        float4 v = in[i];
        ushort4 o;
        o.x = f2bf(v.x); o.y = f2bf(v.y); o.z = f2bf(v.z); o.w = f2bf(v.w);
        out[i] = o;
    }
}

// ============================================================
// CSR build
// ============================================================
__global__ __launch_bounds__(256) void zero_int(int* __restrict__ p, int n) {
    int i = blockIdx.x * 256 + threadIdx.x;
    if (i < n) p[i] = 0;
}

__global__ __launch_bounds__(256) void hist_deg(const int* __restrict__ eu,
                                                const int* __restrict__ ev,
                                                int* __restrict__ cu, int* __restrict__ cv) {
    int e = blockIdx.x * 256 + threadIdx.x;
    if (e >= NEDGE) return;
    atomicAdd(&cu[eu[e]], 1);
    atomicAdd(&cv[ev[e]], 1);
}

// ---- multi-block exclusive scan of cur_u|cur_v (each NROW) ----
// chunk = 1024 elements (256 thr x 4). NCH = 49 chunks per array, grid = 98.
#define NCH 49

__global__ __launch_bounds__(256) void scan_p1(const int* __restrict__ cur_u,
                                               const int* __restrict__ cur_v,
                                               int* __restrict__ bsum) {
    const int arr = blockIdx.x / NCH;
    const int c = blockIdx.x % NCH;
    const int* cur = arr ? cur_v : cur_u;
    int g0 = c * 1024 + threadIdx.x * 4;
    int s = 0;
#pragma unroll
    for (int k = 0; k < 4; k++) {
        int g = g0 + k;
        if (g < NROW) s += cur[g];
    }
    __shared__ int red[256];
    red[threadIdx.x] = s;
    __syncthreads();
    for (int o = 128; o > 0; o >>= 1) {
        if (threadIdx.x < o) red[threadIdx.x] += red[threadIdx.x + o];
        __syncthreads();
    }
    if (threadIdx.x == 0) bsum[blockIdx.x] = red[0];
}

__global__ __launch_bounds__(128) void scan_p2(const int* __restrict__ bsum,
                                               int* __restrict__ bo,
                                               int* __restrict__ off_u, int* __restrict__ off_v) {
    // two independent 49-entry exclusive scans (u in lanes 0-63, v in 64-127)
    int tid = threadIdx.x;
    int half = tid >> 6, l = tid & 63;
    int val = (l < NCH) ? bsum[half * NCH + l] : 0;
    __shared__ int sc[128];
    sc[tid] = val;
    __syncthreads();
    for (int o = 1; o < 64; o <<= 1) {
        int y = (l >= o) ? sc[tid - o] : 0;
        __syncthreads();
        sc[tid] += y;
        __syncthreads();
    }
    if (l < NCH) bo[half * NCH + l] = sc[tid] - val;
    if (tid == 0) { off_u[NROW] = NEDGE; off_v[NROW] = NEDGE; }
}

__global__ __launch_bounds__(256) void scan_p3(const int* __restrict__ cur_u_in,
                                               const int* __restrict__ cur_v_in,
                                               const int* __restrict__ bo,
                                               int* __restrict__ off_u, int* __restrict__ off_v,
                                               int* __restrict__ cur_u, int* __restrict__ cur_v) {
    const int arr = blockIdx.x / NCH;
    const int c = blockIdx.x % NCH;
    const int* in = arr ? cur_v_in : cur_u_in;
    int* off = arr ? off_v : off_u;
    int* cur = arr ? cur_v : cur_u;
    int g0 = c * 1024 + threadIdx.x * 4;
    int v[4], tsum = 0;
#pragma unroll
    for (int k = 0; k < 4; k++) {
        int g = g0 + k;
        v[k] = (g < NROW) ? in[g] : 0;
        tsum += v[k];
    }
    __shared__ int sc[256];
    sc[threadIdx.x] = tsum;
    __syncthreads();
    for (int o = 1; o < 256; o <<= 1) {
        int y = (threadIdx.x >= o) ? sc[threadIdx.x - o] : 0;
        __syncthreads();
        sc[threadIdx.x] += y;
        __syncthreads();
    }
    int excl = bo[blockIdx.x] + sc[threadIdx.x] - tsum;
#pragma unroll
    for (int k = 0; k < 4; k++) {
        int g = g0 + k;
        if (g < NROW) { off[g] = excl; cur[g] = excl; }
        excl += v[k];
    }
}

__global__ __launch_bounds__(256) void deg_k(const int* __restrict__ off_u,
                                             const int* __restrict__ off_v,
                                             int* __restrict__ deg_u, int* __restrict__ deg_v) {
    int i = blockIdx.x * 256 + threadIdx.x;
    if (i < NROW) deg_u[i] = off_u[i + 1] - off_u[i];
    else if (i < 2 * NROW) {
        int j = i - NROW;
        deg_v[j] = off_v[j + 1] - off_v[j];
    }
}

__global__ __launch_bounds__(256) void fill_csr(const int* __restrict__ eu,
                                                const int* __restrict__ ev,
                                                int* __restrict__ cu, int* __restrict__ cv,
                                                int* __restrict__ srt_u, int* __restrict__ srt_v) {
    int e = blockIdx.x * 256 + threadIdx.x;
    if (e >= NEDGE) return;
    int u = eu[e], v = ev[e];
    int p = atomicAdd(&cu[u], 1); srt_u[p] = v;   // u's segment lists v-sources
    int q = atomicAdd(&cv[v], 1); srt_v[q] = u;   // v's segment lists u-sources
}

// ============================================================
// scalar degree aggregations (exact int):
// t[v]  = sum_{seg_v} deg_u[srt_v]      (= S2 deg_u)
// g3[u] = sum_{seg_u} deg_v[srt_u]      (= S3 deg_v)
// g2[u] = sum_{seg_u} t[srt_u]          (= S3 S2 deg_u)
// ============================================================
__global__ __launch_bounds__(256) void t_k(const int* __restrict__ off_v,
                                           const int* __restrict__ srt_v,
                                           const int* __restrict__ deg_u,
                                           int* __restrict__ t) {
    int v = blockIdx.x * 256 + threadIdx.x;
    if (v >= NROW) return;
    int beg = off_v[v], end = off_v[v + 1];
    int s = 0;
    for (int i = beg; i < end; i++) s += deg_u[srt_v[i]];
    t[v] = s;
}

__global__ __launch_bounds__(256) void g23_k(const int* __restrict__ off_u,
                                             const int* __restrict__ srt_u,
                                             const int* __restrict__ deg_v,
                                             const int* __restrict__ t,
                                             int* __restrict__ g2, int* __restrict__ g3) {
    int u = blockIdx.x * 256 + threadIdx.x;
    if (u >= NROW) return;
    int beg = off_u[u], end = off_u[u + 1];
    int a = 0, b = 0;
    for (int i = beg; i < end; i++) {
        int s = srt_u[i];
        a += t[s];
        b += deg_v[s];
    }
    g2[u] = a;
    g3[u] = b;
}

// ============================================================
// micro-GEMMs to fold the weight chain:
// T (130x128) = [W0; b0; b1-copy] @ W1   (row 129 = raw b1 copy)
// P (130x128) = T @ W2 : rows 0-127 = W0W1W2, 128 = b0W1W2, 129 = b1W2
// ============================================================
__global__ __launch_bounds__(128) void small_gemm1(const float* __restrict__ W0,
                                                   const float* __restrict__ b0,
                                                   const float* __restrict__ b1,
                                                   const float* __restrict__ W1,
                                                   float* __restrict__ T) {
    int i = blockIdx.x, j = threadIdx.x;
    if (i == 129) { T[129 * D + j] = b1[j]; return; }
    const float* row = (i < 128) ? (W0 + i * D) : b0;
    __shared__ float R[128];
    R[j] = row[j];
    __syncthreads();
    float acc = 0.f;
#pragma unroll 8
    for (int k = 0; k < 128; k++) acc += R[k] * W1[k * D + j];
    T[i * D + j] = acc;
}

__global__ __launch_bounds__(128) void small_gemm2(const float* __restrict__ T,
                                                   const float* __restrict__ W2,
                                                   float* __restrict__ P) {
    int i = blockIdx.x, j = threadIdx.x;
    __shared__ float R[128];
    R[j] = T[i * D + j];
    __syncthreads();
    float acc = 0.f;
#pragma unroll 8
    for (int k = 0; k < 128; k++) acc += R[k] * W2[k * D + j];
    P[i * D + j] = acc;
}

// ============================================================
// gather_rows: OUTb[r][:] = bf16( sum_{seg r} A[srt[i]][:] )  (bf16 in, bf16 out)
// One wave per dst row; lane l handles cols 2l, 2l+1.
// ============================================================
__global__ __launch_bounds__(256) void gather_rows(const unsigned short* __restrict__ A,
                                                   const int* __restrict__ off,
                                                   const int* __restrict__ srt,
                                                   unsigned short* __restrict__ OUTb) {
    int r = blockIdx.x * 4 + (threadIdx.x >> 6);
    if (r >= NROW) return;
    int lane = threadIdx.x & 63;
    int beg = off[r], end = off[r + 1];
    float ax = 0.f, ay = 0.f;
    int i = beg;
    for (; i + 2 <= end; i += 2) {
        int s0 = srt[i], s1 = srt[i + 1];
        unsigned u0 = *(const unsigned*)(A + (size_t)s0 * D + lane * 2);
        unsigned u1 = *(const unsigned*)(A + (size_t)s1 * D + lane * 2);
        ax += bf2f((unsigned short)(u0 & 0xffff)) + bf2f((unsigned short)(u1 & 0xffff));
        ay += bf2f((unsigned short)(u0 >> 16)) + bf2f((unsigned short)(u1 >> 16));
    }
    if (i < end) {
        int s = srt[i];
        unsigned u0 = *(const unsigned*)(A + (size_t)s * D + lane * 2);
        ax += bf2f((unsigned short)(u0 & 0xffff));
        ay += bf2f((unsigned short)(u0 >> 16));
    }
    unsigned o = (unsigned)f2bf(ax) | ((unsigned)f2bf(ay) << 16);
    *(unsigned*)(OUTb + (size_t)r * D + lane * 2) = o;
}

// ============================================================
// final GEMM + rank-3 bias epilogue:
// OUT[r][j] = sum_k Z[r][k]*Wp[k][j] + g2[r]*c0[j] + g3[r]*c1[j] + deg_u[r]*b2[j]
// Z bf16 [NROW x 128]; Wp/c0/c1 = rows of P; OUT fp32.
// ============================================================
__global__ __launch_bounds__(256) void gemm_final(const unsigned short* __restrict__ Z,
                                                  const float* __restrict__ P,
                                                  const float* __restrict__ b2,
                                                  const int* __restrict__ g2,
                                                  const int* __restrict__ g3,
                                                  const int* __restrict__ du,
                                                  float* __restrict__ OUT) {
    __shared__ float4 Wp[32 * 128];   // 64 KB (k-packed W0W1W2)
    __shared__ float4 Xs[32 * 32];    // 16 KB

    const int tid = threadIdx.x;

    {   // stage Wp k-packed from P rows 0..127
        int j = tid & 127;
        int h = tid >> 7;
        for (int kb = h; kb < 32; kb += 2) {
            float4 w;
            w.x = P[(4 * kb + 0) * D + j];
            w.y = P[(4 * kb + 1) * D + j];
            w.z = P[(4 * kb + 2) * D + j];
            w.w = P[(4 * kb + 3) * D + j];
            Wp[kb * 128 + j] = w;
        }
    }

    const int row0 = blockIdx.x * 32;
    {   // stage Z tile (bf16 -> fp32)
        int k4 = tid & 31;
        int rb = tid >> 5;
        for (int i = 0; i < 4; i++) {
            int r = rb + 8 * i;
            int gr = row0 + r;
            float4 v = make_float4(0.f, 0.f, 0.f, 0.f);
            if (gr < NROW) {
                ushort4 u = ((const ushort4*)(Z + (size_t)gr * D))[k4];
                v.x = bf2f(u.x); v.y = bf2f(u.y); v.z = bf2f(u.z); v.w = bf2f(u.w);
            }
            Xs[r * 32 + k4] = v;
        }
    }
    __syncthreads();

    const int cc = tid & 31;
    const int rr = tid >> 5;

    float acc[4][4];
#pragma unroll
    for (int i = 0; i < 4; i++)
#pragma unroll
        for (int j = 0; j < 4; j++) acc[i][j] = 0.f;

#pragma unroll 4
    for (int kb = 0; kb < 32; kb++) {
        float4 w[4];
#pragma unroll
        for (int j = 0; j < 4; j++) w[j] = Wp[kb * 128 + cc + 32 * j];
        float4 a[4];
#pragma unroll
        for (int i = 0; i < 4; i++) a[i] = Xs[(rr * 4 + i) * 32 + kb];
#pragma unroll
        for (int i = 0; i < 4; i++) {
#pragma unroll
            for (int j = 0; j < 4; j++) {
                acc[i][j] += a[i].x * w[j].x;
                acc[i][j] += a[i].y * w[j].y;
                acc[i][j] += a[i].z * w[j].z;
                acc[i][j] += a[i].w * w[j].w;
            }
        }
    }

    const float* c0 = P + 128 * D;
    const float* c1 = P + 129 * D;
#pragma unroll
    for (int i = 0; i < 4; i++) {
        int gr = row0 + rr * 4 + i;
        if (gr < NROW) {
            float s2 = (float)g2[gr], s3 = (float)g3[gr], sd = (float)du[gr];
            float* yr = OUT + (size_t)gr * D;
#pragma unroll
            for (int j = 0; j < 4; j++) {
                int col = cc + 32 * j;
                yr[col] = acc[i][j] + s2 * c0[col] + s3 * c1[col] + sd * b2[col];
            }
        }
    }
}

// ============================================================
extern "C" void kernel_launch(void* const* d_in, const int* in_sizes, int n_in,
                              void* d_out, int out_size, void* d_ws, size_t ws_size,
                              hipStream_t stream) {
    // 0=X_u(unused), 1=X_v, 2=edge_u, 3=edge_v, 4=W0, 5=b0, 6=W1, 7=b1, 8=W2, 9=b2
    const float* X_v = (const float*)d_in[1];
    const int* edge_u = (const int*)d_in[2];
    const int* edge_v = (const int*)d_in[3];
    const float* W0 = (const float*)d_in[4];
    const float* b0 = (const float*)d_in[5];
    const float* W1 = (const float*)d_in[6];
    const float* b1 = (const float*)d_in[7];
    const float* W2 = (const float*)d_in[8];
    const float* b2 = (const float*)d_in[9];

    // ---- ws layout (~19.7 MB; ws >= 25.6 MB proven) ----
    char* w = (char*)d_ws;
    unsigned short* A = (unsigned short*)w;            // bf16 [NROW x 128] = 12.8 MB
    int* srt_u = (int*)(w + 12800000);                 // 640000
    int* srt_v = srt_u + NEDGE;                        // 640000
    int* off_u = srt_v + NEDGE;                        // 50001 -> pad 50004
    int* off_v = off_u + 50004;
    int* cur_u = off_v + 50004;                        // 50000
    int* cur_v = cur_u + NROW;                         // 50000 (contiguous: zeroed together)
    int* deg_u = cur_v + NROW;                         // 50000
    int* deg_v = deg_u + NROW;                         // 50000
    int* tbuf  = deg_v + NROW;                         // 50000
    int* g2    = tbuf + NROW;                          // 50000
    int* g3    = g2 + NROW;                            // 50000
    int* bsum  = g3 + NROW;                            // 98
    int* bo    = bsum + 128;                           // 98
    float* T   = (float*)(bo + 128);                   // 130*128
    float* P   = T + 130 * D;                          // 130*128

    float* OUT = (float*)d_out;
    unsigned short* B = (unsigned short*)d_out;        // bf16 ping buffer in d_out (dead before final GEMM)

    const dim3 blk(256);
    const int n4 = NROW * D / 4;
    const int edge_grid = (NEDGE + 255) / 256;         // 2500
    const int gath_grid = (NROW + 3) / 4;              // 12500
    const int gemm_grid = (NROW + 31) / 32;            // 1563
    const int row2_grid = (2 * NROW + 255) / 256;      // 391

    // Xb = bf16(X_v) into d_out
    cvt_bf16<<<(n4 + 255) / 256, blk, 0, stream>>>((const float4*)X_v, (ushort4*)B, n4);

    // ---- CSR build (both directions) ----
    zero_int<<<row2_grid, blk, 0, stream>>>(cur_u, 2 * NROW);
    hist_deg<<<edge_grid, blk, 0, stream>>>(edge_u, edge_v, cur_u, cur_v);
    scan_p1<<<2 * NCH, blk, 0, stream>>>(cur_u, cur_v, bsum);
    scan_p2<<<1, dim3(128), 0, stream>>>(bsum, bo, off_u, off_v);
    scan_p3<<<2 * NCH, blk, 0, stream>>>(cur_u, cur_v, bo, off_u, off_v, cur_u, cur_v);
    deg_k<<<row2_grid, blk, 0, stream>>>(off_u, off_v, deg_u, deg_v);
    fill_csr<<<edge_grid, blk, 0, stream>>>(edge_u, edge_v, cur_u, cur_v, srt_u, srt_v);

    // ---- scalar degree aggregations ----
    t_k<<<(NROW + 255) / 256, blk, 0, stream>>>(off_v, srt_v, deg_u, tbuf);
    g23_k<<<(NROW + 255) / 256, blk, 0, stream>>>(off_u, srt_u, deg_v, tbuf, g2, g3);

    // ---- fold weight chain: P = [W0W1W2; b0W1W2; b1W2] ----
    small_gemm1<<<130, dim3(128), 0, stream>>>(W0, b0, b1, W1, T);
    small_gemm2<<<130, dim3(128), 0, stream>>>(T, W2, P);

    // ---- three bf16 aggregation hops: Z = S3 S2 S1 Xb ----
    gather_rows<<<gath_grid, blk, 0, stream>>>(B, off_u, srt_u, A);   // S1: v2u
    gather_rows<<<gath_grid, blk, 0, stream>>>(A, off_v, srt_v, B);   // S2: u2v
    gather_rows<<<gath_grid, blk, 0, stream>>>(B, off_u, srt_u, A);   // S3: v2u

    // ---- final GEMM + exact rank-3 bias epilogue ----
    gemm_final<<<gemm_grid, blk, 0, stream>>>(A, P, b2, g2, g3, deg_u, OUT);
}

// Round 5
// 381.318 us; speedup vs baseline: 9.0794x; 1.1955x over previous
//
#include <hip/hip_runtime.h>

#define D 128
#define NROW 50000      // N_U == N_V == 50000
#define NEDGE 640000
#define NCH 49          // scan chunks per array (1024 elems each)

typedef __attribute__((ext_vector_type(8))) short short8;
typedef __attribute__((ext_vector_type(4))) float f32x4;

__device__ __forceinline__ float bf2f(unsigned short u) {
    return __uint_as_float(((unsigned)u) << 16);
}
__device__ __forceinline__ unsigned short f2bf(float f) {
    unsigned u = __float_as_uint(f);
    unsigned r = (u + 0x7fff + ((u >> 16) & 1)) >> 16;  // round-nearest-even
    return (unsigned short)r;
}
// accumulate packed bf16 pair (lo->e, hi->o)
__device__ __forceinline__ void acc2(float& e, float& o, unsigned g) {
    e += __uint_as_float(g << 16);
    o += __uint_as_float(g & 0xffff0000u);
}

// ============================================================
// prep: fused cvt_bf16 (blocks [0,6250)) + hist_deg ([6250,8750))
//       + small_gemm1 ([8750,8815))
// small_gemm1: T (130x128) = [W0; b0; b1-copy] @ W1
// ============================================================
__global__ __launch_bounds__(256) void prep(const float4* __restrict__ Xv4,
                                            ushort4* __restrict__ Xb4,
                                            const int* __restrict__ eu,
                                            const int* __restrict__ ev,
                                            int* __restrict__ cu, int* __restrict__ cv,
                                            const float* __restrict__ W0,
                                            const float* __restrict__ b0,
                                            const float* __restrict__ b1,
                                            const float* __restrict__ W1,
                                            float* __restrict__ T) {
    const int blk = blockIdx.x, tid = threadIdx.x;
    if (blk < 6250) {                 // cvt: n4 = 1,600,000 = 6250*256 exactly
        int i = blk * 256 + tid;
        float4 v = Xv4[i];
        ushort4 o;
        o.x = f2bf(v.x); o.y = f2bf(v.y); o.z = f2bf(v.z); o.w = f2bf(v.w);
        Xb4[i] = o;
    } else if (blk < 8750) {          // hist: 640,000 = 2500*256 exactly
        int e = (blk - 6250) * 256 + tid;
        atomicAdd(&cu[eu[e]], 1);
        atomicAdd(&cv[ev[e]], 1);
    } else {                          // small_gemm1: rows i = idx*2 + (tid>>7), 130 rows
        __shared__ float R[2][128];
        int idx = blk - 8750;
        int sub = tid >> 7, j = tid & 127;
        int i = idx * 2 + sub;
        bool valid = (i < 130);
        const float* row = nullptr;
        if (valid && i < 128) row = W0 + i * D;
        else if (valid && i == 128) row = b0;
        R[sub][j] = row ? row[j] : 0.f;
        __syncthreads();
        if (!valid) return;
        if (i == 129) { T[129 * D + j] = b1[j]; return; }
        float acc = 0.f;
#pragma unroll 8
        for (int k = 0; k < 128; k++) acc += R[sub][k] * W1[k * D + j];
        T[i * D + j] = acc;
    }
}

// ============================================================
// scan_p1 (blocks [0,98)) + small_gemm2 ([98,163))
// small_gemm2: P (130x128) = T @ W2; also PbT[j][i] = bf16(P[i][j]) for i<128
// ============================================================
__global__ __launch_bounds__(256) void scanp1_sg2(const int* __restrict__ cur_u,
                                                  const int* __restrict__ cur_v,
                                                  int* __restrict__ bsum,
                                                  const float* __restrict__ T,
                                                  const float* __restrict__ W2,
                                                  float* __restrict__ P,
                                                  unsigned short* __restrict__ PbT) {
    const int blk = blockIdx.x, tid = threadIdx.x;
    if (blk < 2 * NCH) {
        const int arr = blk / NCH;
        const int c = blk % NCH;
        const int* cur = arr ? cur_v : cur_u;
        int g0 = c * 1024 + tid * 4;
        int s = 0;
#pragma unroll
        for (int k = 0; k < 4; k++) {
            int g = g0 + k;
            if (g < NROW) s += cur[g];
        }
        __shared__ int red[256];
        red[tid] = s;
        __syncthreads();
        for (int o = 128; o > 0; o >>= 1) {
            if (tid < o) red[tid] += red[tid + o];
            __syncthreads();
        }
        if (tid == 0) bsum[blk] = red[0];
    } else {
        __shared__ float R[2][128];
        int idx = blk - 2 * NCH;
        int sub = tid >> 7, j = tid & 127;
        int i = idx * 2 + sub;
        bool valid = (i < 130);
        R[sub][j] = valid ? T[i * D + j] : 0.f;
        __syncthreads();
        if (!valid) return;
        float acc = 0.f;
#pragma unroll 8
        for (int k = 0; k < 128; k++) acc += R[sub][k] * W2[k * D + j];
        P[i * D + j] = acc;
        if (i < 128) PbT[j * 128 + i] = f2bf(acc);
    }
}

__global__ __launch_bounds__(128) void scan_p2(const int* __restrict__ bsum,
                                               int* __restrict__ bo,
                                               int* __restrict__ off_u, int* __restrict__ off_v) {
    int tid = threadIdx.x;
    int half = tid >> 6, l = tid & 63;
    int val = (l < NCH) ? bsum[half * NCH + l] : 0;
    __shared__ int sc[128];
    sc[tid] = val;
    __syncthreads();
    for (int o = 1; o < 64; o <<= 1) {
        int y = (l >= o) ? sc[tid - o] : 0;
        __syncthreads();
        sc[tid] += y;
        __syncthreads();
    }
    if (l < NCH) bo[half * NCH + l] = sc[tid] - val;
    if (tid == 0) { off_u[NROW] = NEDGE; off_v[NROW] = NEDGE; }
}

// scan_p3: counts -> exclusive offsets (off, cur) + deg output
__global__ __launch_bounds__(256) void scan_p3(const int* __restrict__ cur_u_in,
                                               const int* __restrict__ cur_v_in,
                                               const int* __restrict__ bo,
                                               int* __restrict__ off_u, int* __restrict__ off_v,
                                               int* __restrict__ cur_u, int* __restrict__ cur_v,
                                               int* __restrict__ deg_u, int* __restrict__ deg_v) {
    const int arr = blockIdx.x / NCH;
    const int c = blockIdx.x % NCH;
    const int* in = arr ? cur_v_in : cur_u_in;
    int* off = arr ? off_v : off_u;
    int* cur = arr ? cur_v : cur_u;
    int* deg = arr ? deg_v : deg_u;
    int g0 = c * 1024 + threadIdx.x * 4;
    int v[4], tsum = 0;
#pragma unroll
    for (int k = 0; k < 4; k++) {
        int g = g0 + k;
        v[k] = (g < NROW) ? in[g] : 0;
        tsum += v[k];
    }
    __shared__ int sc[256];
    sc[threadIdx.x] = tsum;
    __syncthreads();
    for (int o = 1; o < 256; o <<= 1) {
        int y = (threadIdx.x >= o) ? sc[threadIdx.x - o] : 0;
        __syncthreads();
        sc[threadIdx.x] += y;
        __syncthreads();
    }
    int excl = bo[blockIdx.x] + sc[threadIdx.x] - tsum;
#pragma unroll
    for (int k = 0; k < 4; k++) {
        int g = g0 + k;
        if (g < NROW) { off[g] = excl; cur[g] = excl; deg[g] = v[k]; }
        excl += v[k];
    }
}

__global__ __launch_bounds__(256) void fill_csr(const int* __restrict__ eu,
                                                const int* __restrict__ ev,
                                                int* __restrict__ cu, int* __restrict__ cv,
                                                int* __restrict__ srt_u, int* __restrict__ srt_v) {
    int e = blockIdx.x * 256 + threadIdx.x;
    if (e >= NEDGE) return;
    int u = eu[e], v = ev[e];
    int p = atomicAdd(&cu[u], 1); srt_u[p] = v;
    int q = atomicAdd(&cv[v], 1); srt_v[q] = u;
}

// t[v] = sum_{seg_v} deg_u[srt_v]   (= S2 deg_u, exact int)
__global__ __launch_bounds__(256) void t_k(const int* __restrict__ off_v,
                                           const int* __restrict__ srt_v,
                                           const int* __restrict__ deg_u,
                                           int* __restrict__ t) {
    int v = blockIdx.x * 256 + threadIdx.x;
    if (v >= NROW) return;
    int beg = off_v[v], end = off_v[v + 1];
    int s = 0;
    for (int i = beg; i < end; i++) s += deg_u[srt_v[i]];
    t[v] = s;
}

// ============================================================
// gather (subwave-16): OUTb[r] = bf16( sum_{seg r} A[srt[i]] )
// 16 lanes per row, uint4 (8 bf16) per lane, unroll 2.
// Optionally fused g23 blocks at the tail (gather1 only).
// ============================================================
__device__ __forceinline__ void gather_body(const unsigned short* __restrict__ A,
                                            const int* __restrict__ off,
                                            const int* __restrict__ srt,
                                            unsigned short* __restrict__ OUTb,
                                            int blk) {
    int r = blk * 16 + (threadIdx.x >> 4);          // 50000 % 16 == 0
    int c = threadIdx.x & 15;                        // 16B chunk within row
    int beg = off[r], end = off[r + 1];
    float a0 = 0.f, a1 = 0.f, a2 = 0.f, a3 = 0.f, a4 = 0.f, a5 = 0.f, a6 = 0.f, a7 = 0.f;
    int i = beg;
    for (; i + 2 <= end; i += 2) {
        int s0 = srt[i], s1 = srt[i + 1];
        uint4 q0 = *(const uint4*)(A + (size_t)s0 * D + c * 8);
        uint4 q1 = *(const uint4*)(A + (size_t)s1 * D + c * 8);
        acc2(a0, a1, q0.x); acc2(a2, a3, q0.y); acc2(a4, a5, q0.z); acc2(a6, a7, q0.w);
        acc2(a0, a1, q1.x); acc2(a2, a3, q1.y); acc2(a4, a5, q1.z); acc2(a6, a7, q1.w);
    }
    if (i < end) {
        uint4 q0 = *(const uint4*)(A + (size_t)srt[i] * D + c * 8);
        acc2(a0, a1, q0.x); acc2(a2, a3, q0.y); acc2(a4, a5, q0.z); acc2(a6, a7, q0.w);
    }
    uint4 o;
    o.x = (unsigned)f2bf(a0) | ((unsigned)f2bf(a1) << 16);
    o.y = (unsigned)f2bf(a2) | ((unsigned)f2bf(a3) << 16);
    o.z = (unsigned)f2bf(a4) | ((unsigned)f2bf(a5) << 16);
    o.w = (unsigned)f2bf(a6) | ((unsigned)f2bf(a7) << 16);
    *(uint4*)(OUTb + (size_t)r * D + c * 8) = o;
}

__global__ __launch_bounds__(256) void gather_rows(const unsigned short* __restrict__ A,
                                                   const int* __restrict__ off,
                                                   const int* __restrict__ srt,
                                                   unsigned short* __restrict__ OUTb) {
    gather_body(A, off, srt, OUTb, blockIdx.x);
}

// gather1 + fused g23: g2[u]=sum t[srt_u], g3[u]=sum deg_v[srt_u]
__global__ __launch_bounds__(256) void gather1_g23(const unsigned short* __restrict__ A,
                                                   const int* __restrict__ off_u,
                                                   const int* __restrict__ srt_u,
                                                   unsigned short* __restrict__ OUTb,
                                                   const int* __restrict__ deg_v,
                                                   const int* __restrict__ t,
                                                   int* __restrict__ g2, int* __restrict__ g3) {
    if (blockIdx.x < 3125) {
        gather_body(A, off_u, srt_u, OUTb, blockIdx.x);
    } else {
        int u = (blockIdx.x - 3125) * 256 + threadIdx.x;
        if (u >= NROW) return;
        int beg = off_u[u], end = off_u[u + 1];
        int a = 0, b = 0;
        for (int i = beg; i < end; i++) {
            int s = srt_u[i];
            a += t[s];
            b += deg_v[s];
        }
        g2[u] = a;
        g3[u] = b;
    }
}

// ============================================================
// MFMA final GEMM + rank-3 fp32 bias epilogue.
// Z bf16 [NROW x 128], PbT bf16 [n][k] 128x128.
// OUT[r][j] = (Z @ W0W1W2)[r][j] + g2[r]*c0[j] + g3[r]*c1[j] + du[r]*b2[j]
// Block 256 = 4 waves; wave handles 16 rows x all 128 cols (8 n-tiles).
// Frags loaded direct from global (L2-hot); no LDS, no barriers.
// ============================================================
__global__ __launch_bounds__(256) void gemm_final_mfma(const unsigned short* __restrict__ Z,
                                                       const unsigned short* __restrict__ PbT,
                                                       const float* __restrict__ P,
                                                       const float* __restrict__ b2,
                                                       const int* __restrict__ g2,
                                                       const int* __restrict__ g3,
                                                       const int* __restrict__ du,
                                                       float* __restrict__ OUT) {
    const int wave = threadIdx.x >> 6;
    const int lane = threadIdx.x & 63;
    const int ml = lane & 15;      // m (A-row / D-col) index
    const int quad = lane >> 4;    // k-quad / D-row-quad
    const int m0 = blockIdx.x * 64 + wave * 16;
    if (m0 >= NROW) return;        // 50000 = 781*64 + 16: block 781 waves 1..3 idle

    const uint4* zr = (const uint4*)(Z + (size_t)(m0 + ml) * D);   // 8 uint4 per row

    f32x4 acc[8];
#pragma unroll
    for (int nt = 0; nt < 8; nt++) acc[nt] = (f32x4){0.f, 0.f, 0.f, 0.f};

#pragma unroll
    for (int kc = 0; kc < 4; kc++) {
        short8 a = __builtin_bit_cast(short8, zr[kc * 4 + quad]);  // A[m][kc*32+quad*8+j]
#pragma unroll
        for (int nt = 0; nt < 8; nt++) {
            const uint4* br = (const uint4*)(PbT + (size_t)(nt * 16 + ml) * D);
            short8 b = __builtin_bit_cast(short8, br[kc * 4 + quad]); // B[k][n], n=nt*16+ml
            acc[nt] = __builtin_amdgcn_mfma_f32_16x16x32_bf16(a, b, acc[nt], 0, 0, 0);
        }
    }

    // per-row scalars (rows r = m0 + quad*4 + reg)
    float sg2[4], sg3[4], sdu[4];
#pragma unroll
    for (int reg = 0; reg < 4; reg++) {
        int r = m0 + quad * 4 + reg;
        sg2[reg] = (float)g2[r];
        sg3[reg] = (float)g3[r];
        sdu[reg] = (float)du[r];
    }
    const float* c0 = P + 128 * D;
    const float* c1 = P + 129 * D;
#pragma unroll
    for (int nt = 0; nt < 8; nt++) {
        int col = nt * 16 + ml;
        float cc0 = c0[col], cc1 = c1[col], cb2 = b2[col];
#pragma unroll
        for (int reg = 0; reg < 4; reg++) {
            int r = m0 + quad * 4 + reg;
            OUT[(size_t)r * D + col] = acc[nt][reg] + sg2[reg] * cc0 + sg3[reg] * cc1 + sdu[reg] * cb2;
        }
    }
}

// ============================================================
extern "C" void kernel_launch(void* const* d_in, const int* in_sizes, int n_in,
                              void* d_out, int out_size, void* d_ws, size_t ws_size,
                              hipStream_t stream) {
    // 0=X_u(unused), 1=X_v, 2=edge_u, 3=edge_v, 4=W0, 5=b0, 6=W1, 7=b1, 8=W2, 9=b2
    const float* X_v = (const float*)d_in[1];
    const int* edge_u = (const int*)d_in[2];
    const int* edge_v = (const int*)d_in[3];
    const float* W0 = (const float*)d_in[4];
    const float* b0 = (const float*)d_in[5];
    const float* W1 = (const float*)d_in[6];
    const float* b1 = (const float*)d_in[7];
    const float* W2 = (const float*)d_in[8];
    const float* b2 = (const float*)d_in[9];

    // ---- ws layout (~19.9 MB; >= 25.6 MB proven available) ----
    char* w = (char*)d_ws;
    unsigned short* A = (unsigned short*)w;            // bf16 [NROW x 128] = 12.8 MB
    int* srt_u = (int*)(w + 12800000);                 // 640000
    int* srt_v = srt_u + NEDGE;                        // 640000
    int* off_u = srt_v + NEDGE;                        // 50004
    int* off_v = off_u + 50004;                        // 50004
    int* cur_u = off_v + 50004;                        // 50000
    int* cur_v = cur_u + NROW;                         // 50000 (contiguous with cur_u: one memset)
    int* deg_u = cur_v + NROW;                         // 50000
    int* deg_v = deg_u + NROW;                         // 50000
    int* tbuf  = deg_v + NROW;                         // 50000
    int* g2    = tbuf + NROW;                          // 50000
    int* g3    = g2 + NROW;                            // 50000
    int* bsum  = g3 + NROW;                            // 98 (pad 128)
    int* bo    = bsum + 128;                           // 98 (pad 128)
    float* T   = (float*)(bo + 128);                   // 130*128
    float* P   = T + 130 * D;                          // 130*128
    unsigned short* PbT = (unsigned short*)(P + 130 * D); // 128*128 bf16 (32 KB)

    float* OUT = (float*)d_out;
    unsigned short* B = (unsigned short*)d_out;        // bf16 ping buffer (dead before final GEMM)

    const dim3 blk(256);

    // cursors to zero (cur_u, cur_v contiguous)
    hipMemsetAsync(cur_u, 0, 2 * NROW * sizeof(int), stream);

    // prep: cvt (6250) + hist (2500) + small_gemm1 (65)
    prep<<<8815, blk, 0, stream>>>((const float4*)X_v, (ushort4*)B, edge_u, edge_v,
                                   cur_u, cur_v, W0, b0, b1, W1, T);
    // scan p1 (98) + small_gemm2 (65)
    scanp1_sg2<<<2 * NCH + 65, blk, 0, stream>>>(cur_u, cur_v, bsum, T, W2, P, PbT);
    scan_p2<<<1, dim3(128), 0, stream>>>(bsum, bo, off_u, off_v);
    scan_p3<<<2 * NCH, blk, 0, stream>>>(cur_u, cur_v, bo, off_u, off_v,
                                         cur_u, cur_v, deg_u, deg_v);
    fill_csr<<<(NEDGE + 255) / 256, blk, 0, stream>>>(edge_u, edge_v, cur_u, cur_v, srt_u, srt_v);
    t_k<<<(NROW + 255) / 256, blk, 0, stream>>>(off_v, srt_v, deg_u, tbuf);

    // hop 1 (v2u) + fused g23
    gather1_g23<<<3125 + 196, blk, 0, stream>>>(B, off_u, srt_u, A, deg_v, tbuf, g2, g3);
    // hop 2 (u2v)
    gather_rows<<<3125, blk, 0, stream>>>(A, off_v, srt_v, B);
    // hop 3 (v2u)
    gather_rows<<<3125, blk, 0, stream>>>(B, off_u, srt_u, A);

    // final MFMA GEMM + exact rank-3 bias epilogue
    gemm_final_mfma<<<782, blk, 0, stream>>>(A, PbT, P, b2, g2, g3, deg_u, OUT);
}